// Round 7
// baseline (669.339 us; speedup 1.0000x reference)
//
#include <hip/hip_runtime.h>
#include <hip/hip_bf16.h>

#define IN_F   4096
#define OUT_F  4096
#define BK     64
#define NTILES (IN_F / BK)   // 64

typedef __bf16 bf16;
typedef __attribute__((ext_vector_type(8)))  __bf16 bf16x8;
typedef __attribute__((ext_vector_type(4)))  __bf16 bf16x4;
typedef __attribute__((ext_vector_type(4)))  float  floatx4;

// ---------------------------------------------------------------------------
// FULLY FUSED single-kernel HQQ GEMM (round-7).
// out(M,N) = x(M,K)fp32 @ dequant(Wp,scale,zero)(N,K)^T + bias.
// R3's 256x256x64 schedule (phases, barriers, XOR swizzle, epilogue) kept
// verbatim; global_load_lds staging replaced by T14 reg-staging:
//   A: 2x float4 from x -> cvt bf16x8 -> ds_write_b128 (swizzled contract
//      preserved: read global unit sun^srow, write stored unit sun).
//   B: 1x int32 packed byte + (scale,zero) -> 8x bit-select -> ds_write_b128.
//      BK=64 == GROUP_SIZE, so one (sc,zp) pair per row per K-tile.
// LD batches issued at R3's STAGE positions; WR one phase later (>=1 MFMA
// cluster of HBM-latency cover). FIFO ledger (steady): batches 6,6,4,4 ->
// per-phase counted waits vmcnt(6)/(6)/(4)/(4); tails vmcnt(0).
// Publication: lgkmcnt(0) before P3-end barrier (raw s_barrier doesn't drain).
// Occupancy is LDS-capped (128 KiB -> 1 block/CU, 2 waves/SIMD, 256-VGPR
// budget) so the ~+35 staging VGPRs cost nothing.
// Eliminates the prep kernel + 128 MB of workspace round-trip entirely
// (diagnostic: the persistent ~200 us non-GEMM gap must now vanish or be
// exposed as fixed harness overhead).
// ---------------------------------------------------------------------------

#define CFENCE asm volatile("" ::: "memory")
#define SBAR() do { CFENCE; __builtin_amdgcn_s_barrier(); CFENCE; } while (0)
#define WAIT_LGKM0 asm volatile("s_waitcnt lgkmcnt(0)" ::: "memory")

// ---- reg-staging: A (x fp32 -> bf16), quarters qa,qb ----------------------
#define LD_A2(nm, qa, qb, kti) do {                                            \
    const int rA_ = (qa) * 64 + wave * 8 + srow;                               \
    const int rB_ = (qb) * 64 + wave * 8 + srow;                               \
    const float* pA_ = X + (size_t)(m0 + rA_) * IN_F + (kti) * BK + gu * 8;    \
    const float* pB_ = X + (size_t)(m0 + rB_) * IN_F + (kti) * BK + gu * 8;    \
    nm##_00 = *(const float4*)pA_;  nm##_01 = *(const float4*)(pA_ + 4);       \
    nm##_10 = *(const float4*)pB_;  nm##_11 = *(const float4*)(pB_ + 4);       \
} while (0)

#define WR_A2(nm, qa, qb, buf) do {                                            \
    const int rA_ = (qa) * 64 + wave * 8 + srow;                               \
    const int rB_ = (qb) * 64 + wave * 8 + srow;                               \
    bf16x8 vA_, vB_;                                                           \
    vA_[0]=(bf16)nm##_00.x; vA_[1]=(bf16)nm##_00.y;                            \
    vA_[2]=(bf16)nm##_00.z; vA_[3]=(bf16)nm##_00.w;                            \
    vA_[4]=(bf16)nm##_01.x; vA_[5]=(bf16)nm##_01.y;                            \
    vA_[6]=(bf16)nm##_01.z; vA_[7]=(bf16)nm##_01.w;                            \
    vB_[0]=(bf16)nm##_10.x; vB_[1]=(bf16)nm##_10.y;                            \
    vB_[2]=(bf16)nm##_10.z; vB_[3]=(bf16)nm##_10.w;                            \
    vB_[4]=(bf16)nm##_11.x; vB_[5]=(bf16)nm##_11.y;                            \
    vB_[6]=(bf16)nm##_11.z; vB_[7]=(bf16)nm##_11.w;                            \
    *(bf16x8*)&(buf)[rA_ * BK + sun * 8] = vA_;                                \
    *(bf16x8*)&(buf)[rB_ * BK + sun * 8] = vB_;                                \
} while (0)

// ---- reg-staging: B (1-bit dequant), quarters qa,qb -----------------------
#define LD_B2(nm, qa, qb, kti) do {                                            \
    const int rA_ = (qa) * 64 + wave * 8 + srow;                               \
    const int rB_ = (qb) * 64 + wave * 8 + srow;                               \
    nm##_w0 = Wp[(size_t)(n0 + rA_) * (IN_F / 8) + (kti) * 8 + gu];            \
    nm##_s0 = scale[(n0 + rA_) * (IN_F / 64) + (kti)];                         \
    nm##_z0 = zero [(n0 + rA_) * (IN_F / 64) + (kti)];                         \
    nm##_w1 = Wp[(size_t)(n0 + rB_) * (IN_F / 8) + (kti) * 8 + gu];            \
    nm##_s1 = scale[(n0 + rB_) * (IN_F / 64) + (kti)];                         \
    nm##_z1 = zero [(n0 + rB_) * (IN_F / 64) + (kti)];                         \
} while (0)

#define WR_B2(nm, qa, qb, buf) do {                                            \
    const int rA_ = (qa) * 64 + wave * 8 + srow;                               \
    const int rB_ = (qb) * 64 + wave * 8 + srow;                               \
    const bf16 hA_ = (bf16)((1.0f - nm##_z0) * nm##_s0);                       \
    const bf16 lA_ = (bf16)(0.0f - nm##_z0 * nm##_s0);                         \
    const bf16 hB_ = (bf16)((1.0f - nm##_z1) * nm##_s1);                       \
    const bf16 lB_ = (bf16)(0.0f - nm##_z1 * nm##_s1);                         \
    bf16x8 vA_, vB_;                                                           \
    _Pragma("unroll")                                                          \
    for (int j_ = 0; j_ < 8; ++j_) vA_[j_] = ((nm##_w0 >> j_) & 1) ? hA_ : lA_;\
    _Pragma("unroll")                                                          \
    for (int j_ = 0; j_ < 8; ++j_) vB_[j_] = ((nm##_w1 >> j_) & 1) ? hB_ : lB_;\
    *(bf16x8*)&(buf)[rA_ * BK + sun * 8] = vA_;                                \
    *(bf16x8*)&(buf)[rB_ * BK + sun * 8] = vB_;                                \
} while (0)

// ---- fragment reads (unchanged from R3) -----------------------------------
#define LDFRAG(tile, row, u) \
    (*(const bf16x8*)((tile) + (row) * BK + (((u) ^ ((row) & 7)) << 3)))

#define LOAD_A(tile, MS)                                                       \
    _Pragma("unroll")                                                          \
    for (int i = 0; i < 4; ++i)                                                \
        _Pragma("unroll")                                                      \
        for (int ks = 0; ks < 2; ++ks)                                         \
            af[i][ks] = LDFRAG((tile), wm * 128 + (MS) * 64 + i * 16 + l15,    \
                               ks * 4 + l4);

#define LOAD_B_TO(dst, tile, NS)                                               \
    _Pragma("unroll")                                                          \
    for (int j = 0; j < 2; ++j)                                                \
        _Pragma("unroll")                                                      \
        for (int ks = 0; ks < 2; ++ks)                                         \
            dst[j][ks] = LDFRAG((tile), wn * 64 + (NS) * 32 + j * 16 + l15,    \
                                ks * 4 + l4);

#define MFMA_QUAD(AI, BJ, BFR)                                                 \
    __builtin_amdgcn_s_setprio(1);                                             \
    _Pragma("unroll")                                                          \
    for (int i = 0; i < 4; ++i)                                                \
        _Pragma("unroll")                                                      \
        for (int j = 0; j < 2; ++j)                                            \
            _Pragma("unroll")                                                  \
            for (int ks = 0; ks < 2; ++ks)                                     \
                acc[(AI) + i][(BJ) + j] =                                      \
                    __builtin_amdgcn_mfma_f32_16x16x32_bf16(                   \
                        af[i][ks], BFR[j][ks], acc[(AI) + i][(BJ) + j], 0, 0, 0); \
    __builtin_amdgcn_s_setprio(0);

__global__ __launch_bounds__(512, 2) void hqq_fused256_kernel(
    const float* __restrict__ X,     // (M, K) fp32
    const int*   __restrict__ Wp,    // (N, K/8) packed bytes in int32
    const float* __restrict__ scale, // (N*K/64,)
    const float* __restrict__ zero,  // (N*K/64,)
    const float* __restrict__ bias,  // (N,)
    float*       __restrict__ out)   // (M, N) fp32
{
    __shared__ __align__(16) bf16 as_[2][256 * BK];   // 64 KiB
    __shared__ __align__(16) bf16 bs_[2][256 * BK];   // 64 KiB

    const int t    = threadIdx.x;
    const int lane = t & 63;
    const int wave = t >> 6;          // 0..7
    const int wm   = wave >> 2;       // 0..1  (M half)
    const int wn   = wave & 3;        // 0..3  (N quarter)
    const int l15  = lane & 15;
    const int l4   = lane >> 4;       // 0..3
    const int srow = lane >> 3;       // staging row within 8-row wave issue
    const int sun  = lane & 7;        // staging stored 16B unit
    const int gu   = sun ^ srow;      // staging global 16B unit (r&7 == srow)

    // XCD-aware chunked swizzle (nwg = 16 * M/256, always a multiple of 8)
    const int nwg = (int)gridDim.x;
    const int cpx = nwg >> 3;
    const int wg  = ((int)blockIdx.x & 7) * cpx + ((int)blockIdx.x >> 3);
    const int n0  = (wg & 15) * 256;   // OUT_F/256 == 16
    const int m0  = (wg >> 4) * 256;

    floatx4 acc[8][4];
#pragma unroll
    for (int f = 0; f < 8; ++f)
#pragma unroll
        for (int g = 0; g < 4; ++g) acc[f][g] = (floatx4){0.f, 0.f, 0.f, 0.f};

    // staging registers (named, loop-carried; never runtime-indexed)
    float4 aq02_00, aq02_01, aq02_10, aq02_11;   // A q0,q2: LD P3 -> WR next P0
    float4 aq13_00, aq13_01, aq13_10, aq13_11;   // A q1,q3: LD P2 -> WR P3
    int   bq01_w0, bq01_w1;  float bq01_s0, bq01_z0, bq01_s1, bq01_z1;  // LD P0 -> WR P1
    int   bq23_w0, bq23_w1;  float bq23_s0, bq23_z0, bq23_s1, bq23_z1;  // LD P1 -> WR P2

    // ---- prologue: tile0 staged synchronously; prime aq02 with tile1 ----
    LD_A2(aq02, 0, 2, 0);
    asm volatile("s_waitcnt vmcnt(0)" ::: "memory");
    WR_A2(aq02, 0, 2, &as_[0][0]);
    LD_A2(aq13, 1, 3, 0);
    asm volatile("s_waitcnt vmcnt(0)" ::: "memory");
    WR_A2(aq13, 1, 3, &as_[0][0]);
    LD_B2(bq01, 0, 1, 0);
    asm volatile("s_waitcnt vmcnt(0)" ::: "memory");
    WR_B2(bq01, 0, 1, &bs_[0][0]);
    LD_B2(bq23, 2, 3, 0);
    asm volatile("s_waitcnt vmcnt(0)" ::: "memory");
    WR_B2(bq23, 2, 3, &bs_[0][0]);
    LD_A2(aq02, 0, 2, 1);              // tile1 A q0,q2 — left in flight (4)
    WAIT_LGKM0;
    SBAR();

    bf16x8 af[4][2], bf0[2][2], bf1[2][2];

    for (int kt = 0; kt < NTILES; ++kt) {
        bf16* const At = &as_[kt & 1][0];
        bf16* const Bt = &bs_[kt & 1][0];
        bf16* const An = &as_[(kt & 1) ^ 1][0];
        bf16* const Bn = &bs_[(kt & 1) ^ 1][0];
        const int s1 = (kt + 1 < NTILES);
        const int s2 = (kt + 2 < NTILES);

        // ---- Phase 0: quadrant (ms=0, ns=0) ----
        LOAD_A(At, 0);
        LOAD_B_TO(bf0, Bt, 0);
        if (s1) {
            LD_B2(bq01, 0, 1, kt + 1);                       // +6
            asm volatile("s_waitcnt vmcnt(6)" ::: "memory"); // aq02 ready
            WR_A2(aq02, 0, 2, An);                           // A(kt+1) q0,q2
        }
        SBAR(); WAIT_LGKM0;
        MFMA_QUAD(0, 0, bf0);
        SBAR();

        // ---- Phase 1: (ms=0, ns=1) — reuses af ----
        LOAD_B_TO(bf1, Bt, 1);
        if (s1) {
            LD_B2(bq23, 2, 3, kt + 1);                       // +6
            asm volatile("s_waitcnt vmcnt(6)" ::: "memory"); // bq01 ready
            WR_B2(bq01, 0, 1, Bn);                           // B(kt+1) q0,q1
        }
        SBAR(); WAIT_LGKM0;
        MFMA_QUAD(0, 2, bf1);
        SBAR();

        // ---- Phase 2: (ms=1, ns=0) — reuses bf0 ----
        LOAD_A(At, 1);
        if (s1) {
            LD_A2(aq13, 1, 3, kt + 1);                       // +4
            asm volatile("s_waitcnt vmcnt(4)" ::: "memory"); // bq23 ready
            WR_B2(bq23, 2, 3, Bn);                           // B(kt+1) q2,q3
        }
        SBAR(); WAIT_LGKM0;
        MFMA_QUAD(4, 0, bf0);
        SBAR();

        // ---- Phase 3: (ms=1, ns=1) — reuses af and bf1; no frag reads ----
        if (s2) LD_A2(aq02, 0, 2, kt + 2);                   // +4 (in flight)
        if (s1) {
            if (s2) { asm volatile("s_waitcnt vmcnt(4)" ::: "memory"); }
            else    { asm volatile("s_waitcnt vmcnt(0)" ::: "memory"); }
            WR_A2(aq13, 1, 3, An);                           // A(kt+1) q1,q3
        }
        MFMA_QUAD(4, 2, bf1);
        // publish tile kt+1: drain my ds_writes before the barrier
        WAIT_LGKM0;
        SBAR();
    }

    // epilogue: C/D layout col=lane&15, row=(lane>>4)*4+reg
#pragma unroll
    for (int g = 0; g < 4; ++g) {
        const int col = n0 + wn * 64 + g * 16 + l15;
        const float bv = bias[col];
#pragma unroll
        for (int f = 0; f < 8; ++f) {
            const int row = m0 + wm * 128 + f * 16 + l4 * 4;
#pragma unroll
            for (int r = 0; r < 4; ++r)
                out[(size_t)(row + r) * OUT_F + col] = acc[f][g][r] + bv;
        }
    }
}

// ---------------------------------------------------------------------------
// Fallback fused kernel (M % 256 != 0) — 128-tile, round-1 version
// ---------------------------------------------------------------------------
#define SA 72
#define SB 72
__global__ __launch_bounds__(256) void hqq_gemm_fused_kernel(
    const float* __restrict__ x, const int* __restrict__ Wp,
    const float* __restrict__ scale, const float* __restrict__ zero,
    const float* __restrict__ bias, float* __restrict__ out)
{
    __shared__ __align__(16) bf16 asmem[128 * SA];
    __shared__ __align__(16) bf16 bsmem[128 * SB];
    const int t = threadIdx.x, lane = t & 63, wave = t >> 6;
    const int lane16 = lane & 15, kq = lane >> 4;
    const int wm = wave >> 1, wn = wave & 1;
    const int n0 = blockIdx.x * 128, m0 = blockIdx.y * 128;
    floatx4 acc[4][4];
#pragma unroll
    for (int i = 0; i < 4; ++i)
#pragma unroll
        for (int j = 0; j < 4; ++j) acc[i][j] = (floatx4){0.f, 0.f, 0.f, 0.f};
    const int a_col4 = t & 15, a_row0 = t >> 4;
    const int b_nl = t >> 1, b_half = t & 1;
    for (int kt = 0; kt < IN_F / 64; ++kt) {
        const float* xp = x + (size_t)(m0 + a_row0) * IN_F + kt * 64 + a_col4 * 4;
#pragma unroll
        for (int p = 0; p < 8; ++p) {
            float4 v = *(const float4*)(xp + (size_t)(p * 16) * IN_F);
            bf16x4 b = { (bf16)v.x, (bf16)v.y, (bf16)v.z, (bf16)v.w };
            *(bf16x4*)&asmem[(a_row0 + p * 16) * SA + a_col4 * 4] = b;
        }
        {
            const int4 v = *(const int4*)(Wp + (size_t)(n0 + b_nl) * (IN_F / 8)
                                          + kt * 8 + b_half * 4);
            const int g = (n0 + b_nl) * (IN_F / 64) + kt;
            const float sc = scale[g], zp = zero[g];
            const bf16 hi = (bf16)((1.0f - zp) * sc), lo = (bf16)(0.0f - zp * sc);
            const int vals[4] = {v.x, v.y, v.z, v.w};
#pragma unroll
            for (int e = 0; e < 4; ++e) {
                bf16x8 w;
#pragma unroll
                for (int j = 0; j < 8; ++j) w[j] = ((vals[e] >> j) & 1) ? hi : lo;
                *(bf16x8*)&bsmem[b_nl * SB + b_half * 32 + e * 8] = w;
            }
        }
        __syncthreads();
#pragma unroll
        for (int ks = 0; ks < 2; ++ks) {
            bf16x8 af[4], bfr[4];
#pragma unroll
            for (int i = 0; i < 4; ++i)
                af[i] = *(const bf16x8*)&asmem[(wm * 64 + i * 16 + lane16) * SA + ks * 32 + kq * 8];
#pragma unroll
            for (int j = 0; j < 4; ++j)
                bfr[j] = *(const bf16x8*)&bsmem[(wn * 64 + j * 16 + lane16) * SB + ks * 32 + kq * 8];
#pragma unroll
            for (int i = 0; i < 4; ++i)
#pragma unroll
                for (int j = 0; j < 4; ++j)
                    acc[i][j] = __builtin_amdgcn_mfma_f32_16x16x32_bf16(af[i], bfr[j], acc[i][j], 0, 0, 0);
        }
        __syncthreads();
    }
#pragma unroll
    for (int j = 0; j < 4; ++j) {
        const int col = n0 + wn * 64 + j * 16 + lane16;
        const float bv = bias[col];
#pragma unroll
        for (int i = 0; i < 4; ++i) {
            const int row = m0 + wm * 64 + i * 16 + kq * 4;
#pragma unroll
            for (int r = 0; r < 4; ++r)
                out[(size_t)(row + r) * OUT_F + col] = acc[i][j][r] + bv;
        }
    }
}

// ---------------------------------------------------------------------------
extern "C" void kernel_launch(void* const* d_in, const int* in_sizes, int n_in,
                              void* d_out, int out_size, void* d_ws, size_t ws_size,
                              hipStream_t stream) {
    const float* x     = (const float*)d_in[0];
    const int*   Wp    = (const int*)d_in[1];
    const float* scale = (const float*)d_in[2];
    const float* zero  = (const float*)d_in[3];
    const float* bias  = (const float*)d_in[4];
    float*       out   = (float*)d_out;

    const int M = in_sizes[0] / IN_F;   // 8192

    if ((M % 256) == 0) {
        // single fused kernel: no prep, no workspace
        hqq_fused256_kernel<<<dim3((OUT_F / 256) * (M / 256)), 512, 0, stream>>>(
            x, Wp, scale, zero, bias, out);
    } else {
        dim3 grid(OUT_F / 128, M / 128);
        hqq_gemm_fused_kernel<<<grid, 256, 0, stream>>>(x, Wp, scale, zero, bias, out);
    }
}